// Round 9
// baseline (121.637 us; speedup 1.0000x reference)
//
#include <hip/hip_runtime.h>
#include <hip/hip_fp16.h>

#define NROWS   16384
#define NCOL    4096
#define NSTAGES 12
#define NPAIRS  2048
#define RPB     4   // rows per block, staged 2-at-a-time through 32 KB LDS

// ---- LDS bank swizzles for the two exchanges (validated R1-R8) ----
__device__ __forceinline__ int swz1(int W) {
  return W ^ (((W >> 8) & 1) << 4) ^ (((W >> 5) & 3) << 2);
}
__device__ __forceinline__ int swz2(int W) {
  return W ^ (((W >> 7) & 1) << 4) ^ (((W >> 5) & 3) << 2);
}

// pair index needed by lane t, stage s, sub-pair p (matches butterfly layouts)
__device__ __forceinline__ int pair_idx(int s, int t, int p) {
  int thi = t >> 4, tlo = t & 15;
  return (s < 4) ? (t * 8 + p) : (s < 8) ? (thi * 128 + p * 16 + tlo) : (p * 256 + t);
}

// fp16 packed table: tabq[(s*2+h)*256 + t] = uint4 of 4 half2 {cos,sin},
// pairs p = 4h..4h+3 for lane t, stage s. fp16 accuracy validated R6-R8
// (absmax 0.031 < 0.1175 threshold).
__global__ void cs_table_kernel(const float* __restrict__ ang, uint4* __restrict__ tabq) {
  int tid = blockIdx.x * blockDim.x + threadIdx.x;
  if (tid >= NSTAGES * 2 * 256) return;
  int s = tid >> 9;
  int h = (tid >> 8) & 1;
  int t = tid & 255;
  unsigned r[4];
#pragma unroll
  for (int e = 0; e < 4; ++e) {
    int pr = pair_idx(s, t, 4 * h + e);
    float sv, cv;
    sincosf(ang[s * NPAIRS + pr], &sv, &cv);
    __half2 hh = __floats2half2_rn(cv, sv);
    r[e] = *reinterpret_cast<unsigned*>(&hh);
  }
  tabq[tid] = make_uint4(r[0], r[1], r[2], r[3]);
}

__device__ __forceinline__ float2 h2f(unsigned u) {
  __half2 h = *reinterpret_cast<__half2*>(&u);
  return __half22float2(h);
}

// load one stage's 8 rotation pairs for lane t (2 dwordx4, fp16-packed)
template <bool TAB>
__device__ __forceinline__ void load_A(int s, int t, const uint4* __restrict__ tabq,
                                       const float* __restrict__ ang, float2* A) {
  if constexpr (TAB) {
    uint4 qa = tabq[(s * 2 + 0) * 256 + t];
    uint4 qb = tabq[(s * 2 + 1) * 256 + t];
    A[0] = h2f(qa.x); A[1] = h2f(qa.y); A[2] = h2f(qa.z); A[3] = h2f(qa.w);
    A[4] = h2f(qb.x); A[5] = h2f(qb.y); A[6] = h2f(qb.z); A[7] = h2f(qb.w);
  } else {
#pragma unroll
    for (int p = 0; p < 8; ++p) {
      float sv, cv;
      sincosf(ang[s * NPAIRS + pair_idx(s, t, p)], &sv, &cv);
      A[p] = make_float2(cv, sv);
    }
  }
}

// wave-lockstep LDS fence (validated R5-R8): lgkmcnt(0) + scheduling pin
__device__ __forceinline__ void wave_lds_fence() {
  asm volatile("s_waitcnt lgkmcnt(0)" ::: "memory");
  __builtin_amdgcn_sched_barrier(0);
}

template <bool TAB>
__global__ __launch_bounds__(256, 4) void butterfly_kernel(
    const float* __restrict__ x, const uint4* __restrict__ tabq,
    const float* __restrict__ ang, float* __restrict__ out) {
  __shared__ __align__(16) float lds[2][NCOL];   // 32 KB: 2 rows at a time

  const int t   = threadIdx.x;
  const int w   = t >> 6;   // wave id
  const int l   = t & 63;   // lane id
  const int thi = t >> 4;
  const int tlo = t & 15;
  const size_t row0 = (size_t)blockIdx.x * RPB;

  float v[RPB][16];

  // ---- staging, sub-pass A (rows 0,1): wave-local chunks, swizzled ds_write ----
  {
    float4 st[2][4];
#pragma unroll
    for (int r = 0; r < 2; ++r) {
      const float4* row4 = reinterpret_cast<const float4*>(x + (row0 + r) * NCOL);
#pragma unroll
      for (int k = 0; k < 4; ++k)
        st[r][k] = row4[256 * w + 64 * k + l];
    }
#pragma unroll
    for (int r = 0; r < 2; ++r)
#pragma unroll
      for (int k = 0; k < 4; ++k) {
        const int c  = 256 * w + 64 * k + l;
        const int cs = c ^ ((c >> 3) & 7);
        *reinterpret_cast<float4*>(&lds[r][cs * 4]) = st[r][k];
      }
  }
  // issue rows 2,3 loads now; latency hides under sub-pass-A frag reads
  float4 st2[2][4];
#pragma unroll
  for (int r = 0; r < 2; ++r) {
    const float4* row4 = reinterpret_cast<const float4*>(x + (row0 + 2 + r) * NCOL);
#pragma unroll
    for (int k = 0; k < 4; ++k)
      st2[r][k] = row4[256 * w + 64 * k + l];
  }
  wave_lds_fence();
#pragma unroll
  for (int r = 0; r < 2; ++r)
#pragma unroll
    for (int k = 0; k < 4; ++k) {
      int ba = (t * 64 + k * 16) ^ (((t >> 1) & 7) << 4);
      float4 q = *reinterpret_cast<const float4*>(
          reinterpret_cast<const char*>(&lds[r][0]) + ba);
      v[r][4 * k + 0] = q.x; v[r][4 * k + 1] = q.y;
      v[r][4 * k + 2] = q.z; v[r][4 * k + 3] = q.w;
    }
  wave_lds_fence();   // frag reads done before overwrite

  // ---- staging, sub-pass B (rows 2,3) through the same buffers ----
#pragma unroll
  for (int r = 0; r < 2; ++r)
#pragma unroll
    for (int k = 0; k < 4; ++k) {
      const int c  = 256 * w + 64 * k + l;
      const int cs = c ^ ((c >> 3) & 7);
      *reinterpret_cast<float4*>(&lds[r][cs * 4]) = st2[r][k];
    }
  wave_lds_fence();
#pragma unroll
  for (int r = 0; r < 2; ++r)
#pragma unroll
    for (int k = 0; k < 4; ++k) {
      int ba = (t * 64 + k * 16) ^ (((t >> 1) & 7) << 4);
      float4 q = *reinterpret_cast<const float4*>(
          reinterpret_cast<const char*>(&lds[r][0]) + ba);
      v[2 + r][4 * k + 0] = q.x; v[2 + r][4 * k + 1] = q.y;
      v[2 + r][4 * k + 2] = q.z; v[2 + r][4 * k + 3] = q.w;
    }

  float2 A[8];

  // ---- phase 1: stages 0..3 — ONE table load per stage for 4 rows ----
#pragma unroll
  for (int s = 0; s < 4; ++s) {
    load_A<TAB>(s, t, tabq, ang, A);
    const int qq = s & 3, d = 1 << qq;
#pragma unroll
    for (int r = 0; r < RPB; ++r) {
#pragma unroll
      for (int p = 0; p < 8; ++p) {
        const int j0 = ((p >> qq) << (qq + 1)) | (p & (d - 1));
        const int j1 = j0 + d;
        float v0 = v[r][j0], v1 = v[r][j1];
        v[r][j0] = A[p].x * v0 - A[p].y * v1;
        v[r][j1] = A[p].y * v0 + A[p].x * v1;
      }
    }
  }

  // ---- exchange 1 (wave-local), two sub-passes through 2-row LDS ----
  wave_lds_fence();   // phase-1 frag source reuse safe (regs only) — cheap guard
#pragma unroll
  for (int r = 0; r < 2; ++r)
#pragma unroll
    for (int j = 0; j < 16; ++j)
      lds[r][swz1(thi * 256 + j * 16 + tlo)] = v[r][j];
  wave_lds_fence();
#pragma unroll
  for (int r = 0; r < 2; ++r)
#pragma unroll
    for (int k = 0; k < 4; ++k) {
      float4 q = *reinterpret_cast<const float4*>(&lds[r][swz1(thi * 256 + tlo * 16 + 4 * k)]);
      v[r][4 * k + 0] = q.x; v[r][4 * k + 1] = q.y;
      v[r][4 * k + 2] = q.z; v[r][4 * k + 3] = q.w;
    }
  wave_lds_fence();
#pragma unroll
  for (int r = 0; r < 2; ++r)
#pragma unroll
    for (int j = 0; j < 16; ++j)
      lds[r][swz1(thi * 256 + j * 16 + tlo)] = v[2 + r][j];
  wave_lds_fence();
#pragma unroll
  for (int r = 0; r < 2; ++r)
#pragma unroll
    for (int k = 0; k < 4; ++k) {
      float4 q = *reinterpret_cast<const float4*>(&lds[r][swz1(thi * 256 + tlo * 16 + 4 * k)]);
      v[2 + r][4 * k + 0] = q.x; v[2 + r][4 * k + 1] = q.y;
      v[2 + r][4 * k + 2] = q.z; v[2 + r][4 * k + 3] = q.w;
    }

  // ---- phase 2: stages 4..7 ----
#pragma unroll
  for (int s = 4; s < 8; ++s) {
    load_A<TAB>(s, t, tabq, ang, A);
    const int qq = s & 3, d = 1 << qq;
#pragma unroll
    for (int r = 0; r < RPB; ++r) {
#pragma unroll
      for (int p = 0; p < 8; ++p) {
        const int j0 = ((p >> qq) << (qq + 1)) | (p & (d - 1));
        const int j1 = j0 + d;
        float v0 = v[r][j0], v1 = v[r][j1];
        v[r][j0] = A[p].x * v0 - A[p].y * v1;
        v[r][j1] = A[p].y * v0 + A[p].x * v1;
      }
    }
  }

  // ---- exchange 2 (cross-wave), two sub-passes, block barriers ----
  __syncthreads();
#pragma unroll
  for (int r = 0; r < 2; ++r)
#pragma unroll
    for (int j = 0; j < 16; ++j)
      lds[r][swz2(j * 256 + tlo * 16 + thi)] = v[r][j];
  __syncthreads();
#pragma unroll
  for (int r = 0; r < 2; ++r)
#pragma unroll
    for (int k = 0; k < 4; ++k) {
      float4 q = *reinterpret_cast<const float4*>(&lds[r][swz2(thi * 256 + tlo * 16 + 4 * k)]);
      v[r][4 * k + 0] = q.x; v[r][4 * k + 1] = q.y;
      v[r][4 * k + 2] = q.z; v[r][4 * k + 3] = q.w;
    }
  __syncthreads();
#pragma unroll
  for (int r = 0; r < 2; ++r)
#pragma unroll
    for (int j = 0; j < 16; ++j)
      lds[r][swz2(j * 256 + tlo * 16 + thi)] = v[2 + r][j];
  __syncthreads();
#pragma unroll
  for (int r = 0; r < 2; ++r)
#pragma unroll
    for (int k = 0; k < 4; ++k) {
      float4 q = *reinterpret_cast<const float4*>(&lds[r][swz2(thi * 256 + tlo * 16 + 4 * k)]);
      v[2 + r][4 * k + 0] = q.x; v[2 + r][4 * k + 1] = q.y;
      v[2 + r][4 * k + 2] = q.z; v[2 + r][4 * k + 3] = q.w;
    }

  // ---- phase 3: stages 8..11 ----
#pragma unroll
  for (int s = 8; s < 12; ++s) {
    load_A<TAB>(s, t, tabq, ang, A);
    const int qq = s & 3, d = 1 << qq;
#pragma unroll
    for (int r = 0; r < RPB; ++r) {
#pragma unroll
      for (int p = 0; p < 8; ++p) {
        const int j0 = ((p >> qq) << (qq + 1)) | (p & (d - 1));
        const int j1 = j0 + d;
        float v0 = v[r][j0], v1 = v[r][j1];
        v[r][j0] = A[p].x * v0 - A[p].y * v1;
        v[r][j1] = A[p].y * v0 + A[p].x * v1;
      }
    }
  }

  // ---- store (elem i*256 + t: lanes contiguous, coalesced) ----
#pragma unroll
  for (int r = 0; r < RPB; ++r) {
    float* orow = out + (row0 + r) * NCOL;
#pragma unroll
    for (int i = 0; i < 16; ++i)
      orow[i * 256 + t] = v[r][i];
  }
}

extern "C" void kernel_launch(void* const* d_in, const int* in_sizes, int n_in,
                              void* d_out, int out_size, void* d_ws, size_t ws_size,
                              hipStream_t stream) {
  const float* x   = (const float*)d_in[0];
  const float* ang = (const float*)d_in[1];
  float* out       = (float*)d_out;

  const size_t tab_bytes = (size_t)NSTAGES * 2 * 256 * sizeof(uint4);  // 96 KB
  const int nblocks = NROWS / RPB;  // 4096

  if (ws_size >= tab_bytes) {
    uint4* tabq = (uint4*)d_ws;
    cs_table_kernel<<<(NSTAGES * 2 * 256 + 255) / 256, 256, 0, stream>>>(ang, tabq);
    butterfly_kernel<true><<<nblocks, 256, 0, stream>>>(x, tabq, nullptr, out);
  } else {
    butterfly_kernel<false><<<nblocks, 256, 0, stream>>>(x, nullptr, ang, out);
  }
}

// Round 10
// 113.698 us; speedup vs baseline: 1.0698x; 1.0698x over previous
//
#include <hip/hip_runtime.h>
#include <hip/hip_fp16.h>

#define NROWS   16384
#define NCOL    4096
#define NSTAGES 12
#define NPAIRS  2048
#define RPB     2   // rows per block (32 KB LDS) — R8 proven shape

// ---- LDS bank swizzles for the two exchanges (validated R1-R9) ----
__device__ __forceinline__ int swz1(int W) {
  return W ^ (((W >> 8) & 1) << 4) ^ (((W >> 5) & 3) << 2);
}
__device__ __forceinline__ int swz2(int W) {
  return W ^ (((W >> 7) & 1) << 4) ^ (((W >> 5) & 3) << 2);
}

// pair index needed by lane t, stage s, sub-pair p (matches butterfly layouts)
__device__ __forceinline__ int pair_idx(int s, int t, int p) {
  int thi = t >> 4, tlo = t & 15;
  return (s < 4) ? (t * 8 + p) : (s < 8) ? (thi * 128 + p * 16 + tlo) : (p * 256 + t);
}

// fp16 packed table: tabq[(s*2+h)*256 + t] = uint4 of 4 half2 {cos,sin},
// pairs p = 4h..4h+3 for lane t, stage s. fp16 accuracy validated R6-R9
// (absmax 0.031 < 0.1175 threshold).
__global__ void cs_table_kernel(const float* __restrict__ ang, uint4* __restrict__ tabq) {
  int tid = blockIdx.x * blockDim.x + threadIdx.x;
  if (tid >= NSTAGES * 2 * 256) return;
  int s = tid >> 9;
  int h = (tid >> 8) & 1;
  int t = tid & 255;
  unsigned r[4];
#pragma unroll
  for (int e = 0; e < 4; ++e) {
    int pr = pair_idx(s, t, 4 * h + e);
    float sv, cv;
    sincosf(ang[s * NPAIRS + pr], &sv, &cv);
    __half2 hh = __floats2half2_rn(cv, sv);
    r[e] = *reinterpret_cast<unsigned*>(&hh);
  }
  tabq[tid] = make_uint4(r[0], r[1], r[2], r[3]);
}

__device__ __forceinline__ float2 h2f(unsigned u) {
  __half2 h = *reinterpret_cast<__half2*>(&u);
  return __half22float2(h);
}

// wave-lockstep LDS fence (validated R5-R9)
__device__ __forceinline__ void wave_lds_fence() {
  asm volatile("s_waitcnt lgkmcnt(0)" ::: "memory");
  __builtin_amdgcn_sched_barrier(0);
}

// block barrier WITHOUT vmcnt drain (validated R6/R7): keeps the phase-3
// table prefetch in flight across the exchange-2 barrier.
__device__ __forceinline__ void block_barrier_lgkm() {
  asm volatile("s_waitcnt lgkmcnt(0)" ::: "memory");
  __builtin_amdgcn_sched_barrier(0);
  __builtin_amdgcn_s_barrier();
  __builtin_amdgcn_sched_barrier(0);
}

// table prefetch for one stage (2 dwordx4); no-op in fallback mode
template <bool TAB>
__device__ __forceinline__ void fetch_stage(const uint4* __restrict__ tabq, int s, int t,
                                            uint4& qa, uint4& qb) {
  if constexpr (TAB) {
    qa = tabq[(s * 2 + 0) * 256 + t];
    qb = tabq[(s * 2 + 1) * 256 + t];
  }
}

// one butterfly stage on 2 rows packed as float2 (identical op on .x/.y ->
// SLP-vectorizable to v_pk_fma_f32 / v_pk_mul_f32)
template <bool TAB>
__device__ __forceinline__ void stage_math(int sg, int sl, uint4 qa, uint4 qb,
                                           const float* __restrict__ ang, int t,
                                           float2* v2) {
  const int d = 1 << sl;
  const unsigned aw[8] = {qa.x, qa.y, qa.z, qa.w, qb.x, qb.y, qb.z, qb.w};
#pragma unroll
  for (int p = 0; p < 8; ++p) {
    float2 A;
    if constexpr (TAB) {
      A = h2f(aw[p]);
    } else {
      float sv, cv;
      sincosf(ang[sg * NPAIRS + pair_idx(sg, t, p)], &sv, &cv);
      A = make_float2(cv, sv);
    }
    const int j0 = ((p >> sl) << (sl + 1)) | (p & (d - 1));
    const int j1 = j0 + d;
    float2 v0 = v2[j0], v1 = v2[j1];
    v2[j0] = make_float2(A.x * v0.x - A.y * v1.x, A.x * v0.y - A.y * v1.y);
    v2[j1] = make_float2(A.y * v0.x + A.x * v1.x, A.y * v0.y + A.x * v1.y);
  }
}

template <bool TAB>
__global__ __launch_bounds__(256, 4) void butterfly_kernel(
    const float* __restrict__ x, const uint4* __restrict__ tabq,
    const float* __restrict__ ang, float* __restrict__ out) {
  __shared__ __align__(16) float lds[RPB][NCOL];

  const int t   = threadIdx.x;
  const int w   = t >> 6;   // wave id
  const int l   = t & 63;   // lane id
  const int thi = t >> 4;
  const int tlo = t & 15;
  const size_t row0 = (size_t)blockIdx.x * RPB;

  // ---- staging global loads FIRST (oldest vmcnt entries: the ds_write's
  //      implicit wait on st does not drain the table loads issued after) ----
  float4 st[RPB][4];
#pragma unroll
  for (int r = 0; r < RPB; ++r) {
    const float4* row4 = reinterpret_cast<const float4*>(x + (row0 + r) * NCOL);
#pragma unroll
    for (int k = 0; k < 4; ++k)
      st[r][k] = row4[256 * w + 64 * k + l];
  }

  // ---- phase-1 table prefetch: overlaps staging HBM latency ----
  uint4 qa0, qb0, qa1, qb1, qa2, qb2, qa3, qb3;
  fetch_stage<TAB>(tabq, 0, t, qa0, qb0);
  fetch_stage<TAB>(tabq, 1, t, qa1, qb1);
  fetch_stage<TAB>(tabq, 2, t, qa2, qb2);
  fetch_stage<TAB>(tabq, 3, t, qa3, qb3);

  // ---- stage to LDS: wave-local, swizzled sigma(c)=c^((c>>3)&7) ----
#pragma unroll
  for (int r = 0; r < RPB; ++r) {
#pragma unroll
    for (int k = 0; k < 4; ++k) {
      const int c  = 256 * w + 64 * k + l;
      const int cs = c ^ ((c >> 3) & 7);
      *reinterpret_cast<float4*>(&lds[r][cs * 4]) = st[r][k];
    }
  }
  wave_lds_fence();

  // ---- phase-1 fragment read, rows packed into float2 ----
  float2 v2[16];
#pragma unroll
  for (int k = 0; k < 4; ++k) {
    int ba = (t * 64 + k * 16) ^ (((t >> 1) & 7) << 4);  // swizzled byte addr
    float4 q0 = *reinterpret_cast<const float4*>(
        reinterpret_cast<const char*>(&lds[0][0]) + ba);
    float4 q1 = *reinterpret_cast<const float4*>(
        reinterpret_cast<const char*>(&lds[1][0]) + ba);
    v2[4 * k + 0] = make_float2(q0.x, q1.x);
    v2[4 * k + 1] = make_float2(q0.y, q1.y);
    v2[4 * k + 2] = make_float2(q0.z, q1.z);
    v2[4 * k + 3] = make_float2(q0.w, q1.w);
  }

  // ---- phase 1: stages 0..3 ----
  stage_math<TAB>(0, 0, qa0, qb0, ang, t, v2);
  stage_math<TAB>(1, 1, qa1, qb1, ang, t, v2);
  stage_math<TAB>(2, 2, qa2, qb2, ang, t, v2);
  stage_math<TAB>(3, 3, qa3, qb3, ang, t, v2);

  // ---- phase-2 table prefetch: L2 latency hides under exchange 1 ----
  uint4 pa0, pb0, pa1, pb1, pa2, pb2, pa3, pb3;
  fetch_stage<TAB>(tabq, 4, t, pa0, pb0);
  fetch_stage<TAB>(tabq, 5, t, pa1, pb1);
  fetch_stage<TAB>(tabq, 6, t, pa2, pb2);
  fetch_stage<TAB>(tabq, 7, t, pa3, pb3);

  // ---- exchange 1 (wave-local: quarter n[11:10]=w) ----
#pragma unroll
  for (int j = 0; j < 16; ++j) {
    lds[0][swz1(thi * 256 + j * 16 + tlo)] = v2[j].x;
    lds[1][swz1(thi * 256 + j * 16 + tlo)] = v2[j].y;
  }
  wave_lds_fence();
#pragma unroll
  for (int k = 0; k < 4; ++k) {
    float4 q0 = *reinterpret_cast<const float4*>(&lds[0][swz1(thi * 256 + tlo * 16 + 4 * k)]);
    float4 q1 = *reinterpret_cast<const float4*>(&lds[1][swz1(thi * 256 + tlo * 16 + 4 * k)]);
    v2[4 * k + 0] = make_float2(q0.x, q1.x);
    v2[4 * k + 1] = make_float2(q0.y, q1.y);
    v2[4 * k + 2] = make_float2(q0.z, q1.z);
    v2[4 * k + 3] = make_float2(q0.w, q1.w);
  }

  // ---- phase 2: stages 4..7 ----
  stage_math<TAB>(4, 0, pa0, pb0, ang, t, v2);
  stage_math<TAB>(5, 1, pa1, pb1, ang, t, v2);
  stage_math<TAB>(6, 2, pa2, pb2, ang, t, v2);
  stage_math<TAB>(7, 3, pa3, pb3, ang, t, v2);

  // ---- phase-3 table prefetch: stays in flight across the raw barriers ----
  uint4 ra0, rb0, ra1, rb1, ra2, rb2, ra3, rb3;
  fetch_stage<TAB>(tabq, 8, t, ra0, rb0);
  fetch_stage<TAB>(tabq, 9, t, ra1, rb1);
  fetch_stage<TAB>(tabq, 10, t, ra2, rb2);
  fetch_stage<TAB>(tabq, 11, t, ra3, rb3);

  // ---- exchange 2 (cross-wave): raw barriers, no vmcnt drain ----
  block_barrier_lgkm();
#pragma unroll
  for (int j = 0; j < 16; ++j) {
    lds[0][swz2(j * 256 + tlo * 16 + thi)] = v2[j].x;
    lds[1][swz2(j * 256 + tlo * 16 + thi)] = v2[j].y;
  }
  block_barrier_lgkm();
#pragma unroll
  for (int k = 0; k < 4; ++k) {
    float4 q0 = *reinterpret_cast<const float4*>(&lds[0][swz2(thi * 256 + tlo * 16 + 4 * k)]);
    float4 q1 = *reinterpret_cast<const float4*>(&lds[1][swz2(thi * 256 + tlo * 16 + 4 * k)]);
    v2[4 * k + 0] = make_float2(q0.x, q1.x);
    v2[4 * k + 1] = make_float2(q0.y, q1.y);
    v2[4 * k + 2] = make_float2(q0.z, q1.z);
    v2[4 * k + 3] = make_float2(q0.w, q1.w);
  }

  // ---- phase 3: stages 8..11 ----
  stage_math<TAB>(8, 0, ra0, rb0, ang, t, v2);
  stage_math<TAB>(9, 1, ra1, rb1, ang, t, v2);
  stage_math<TAB>(10, 2, ra2, rb2, ang, t, v2);
  stage_math<TAB>(11, 3, ra3, rb3, ang, t, v2);

  // ---- store (elem i*256 + t: lanes contiguous, coalesced) ----
  float* orow0 = out + (row0 + 0) * NCOL;
  float* orow1 = out + (row0 + 1) * NCOL;
#pragma unroll
  for (int i = 0; i < 16; ++i) {
    orow0[i * 256 + t] = v2[i].x;
    orow1[i * 256 + t] = v2[i].y;
  }
}

extern "C" void kernel_launch(void* const* d_in, const int* in_sizes, int n_in,
                              void* d_out, int out_size, void* d_ws, size_t ws_size,
                              hipStream_t stream) {
  const float* x   = (const float*)d_in[0];
  const float* ang = (const float*)d_in[1];
  float* out       = (float*)d_out;

  const size_t tab_bytes = (size_t)NSTAGES * 2 * 256 * sizeof(uint4);  // 96 KB
  const int nblocks = NROWS / RPB;  // 8192

  if (ws_size >= tab_bytes) {
    uint4* tabq = (uint4*)d_ws;
    cs_table_kernel<<<(NSTAGES * 2 * 256 + 255) / 256, 256, 0, stream>>>(ang, tabq);
    butterfly_kernel<true><<<nblocks, 256, 0, stream>>>(x, tabq, nullptr, out);
  } else {
    butterfly_kernel<false><<<nblocks, 256, 0, stream>>>(x, nullptr, ang, out);
  }
}